// Round 3
// baseline (318.992 us; speedup 1.0000x reference)
//
#include <hip/hip_runtime.h>

typedef unsigned short u16;
typedef unsigned int   u32;
typedef __attribute__((ext_vector_type(8))) __bf16 bf16x8;
typedef __attribute__((ext_vector_type(4))) float  f32x4;

#define L_SEQ  2048
#define BATCH  8
#define DIM    1024
#define ROWS   (L_SEQ*BATCH)     /* 16384 */
#define N3     (3*DIM)           /* 3072  */
#define NCHUNK 32
#define LCHUNK (L_SEQ/NCHUNK)    /* 64    */
#define NCHAIN (BATCH*DIM)       /* 8192  */

__device__ __forceinline__ float b2f(u16 h) {
  return __builtin_bit_cast(float, (u32)h << 16);
}
__device__ __forceinline__ u32 pk2(float a, float b) {   // pack 2 f32 -> 2 bf16 RNE
  u32 r;
  asm("v_cvt_pk_bf16_f32 %0, %1, %2" : "=v"(r) : "v"(a), "v"(b));
  return r;
}
__device__ __forceinline__ u16 f2b(float f) {
  u32 u = __builtin_bit_cast(u32, f);
  return (u16)((u + 0x7fffu + ((u >> 16) & 1u)) >> 16);
}

// ---------------- K0: convert x (and W) f32 -> bf16, vectorized ----------------
__global__ void k_convert(const float* __restrict__ x, const float* __restrict__ W,
                          u16* __restrict__ xb, u16* __restrict__ wb) {
  const int NX4 = (ROWS * DIM) / 4;   // 4194304
  const int NW4 = (N3 * DIM) / 4;     // 786432
  int i = blockIdx.x * blockDim.x + threadIdx.x;
  const int stride = gridDim.x * blockDim.x;
  for (; i < NX4 + NW4; i += stride) {
    const float4* s; u16* d; int j;
    if (i < NX4) { s = (const float4*)x; d = xb; j = i; }
    else         { s = (const float4*)W; d = wb; j = i - NX4; }
    float4 v = s[j];
    uint2 o; o.x = pk2(v.x, v.y); o.y = pk2(v.z, v.w);
    *(uint2*)(d + 4 * (size_t)j) = o;
  }
}

// ---------------- K1 fast: bf16 GEMM via global_load_lds (m97 structure) -------
__device__ __forceinline__ void gl_lds16(const u16* g, u16* l) {
  __builtin_amdgcn_global_load_lds((const __attribute__((address_space(1))) void*)g,
                                   (__attribute__((address_space(3))) void*)l,
                                   16, 0, 0);
}

__global__ __launch_bounds__(256) void k_gemm_lds(const u16* __restrict__ A,  // ROWS x DIM bf16
                                                  const u16* __restrict__ B,  // N3 x DIM bf16
                                                  u16* __restrict__ C) {      // ROWS x N3 bf16
  __shared__ u16 lds[8192];                       // A 128x32 | B 128x32
  const int tid  = threadIdx.x;
  const int lane = tid & 63;
  const int wid  = tid >> 6;                      // 4 waves, 2x2 of 64x64
  const int wm = wid >> 1, wn = wid & 1;
  const int lr = lane & 15, lk = lane >> 4;
  const int mBase = blockIdx.y << 7;
  const int nBase = blockIdx.x << 7;

  f32x4 acc[4][4] = {};

  // staging: wave wid stages A rows [wid*32, wid*32+32) in two 16-row chunks
  const int sRow = lane >> 2;                     // 0..15
  const int sCol = (lane & 3) << 3;               // elem 0,8,16,24
  const u16* gA = A + (size_t)(mBase + wid * 32 + sRow) * DIM + sCol;
  const u16* gB = B + (size_t)(nBase + wid * 32 + sRow) * DIM + sCol;
  u16* lA0 = &lds[wid * 1024];
  u16* lA1 = &lds[wid * 1024 + 512];
  u16* lB0 = &lds[4096 + wid * 1024];
  u16* lB1 = &lds[4096 + wid * 1024 + 512];

  const int aoff = (wm * 64 + lr) * 32 + lk * 8;
  const int boff = 4096 + (wn * 64 + lr) * 32 + lk * 8;

  for (int k0 = 0; k0 < DIM; k0 += 32) {
    gl_lds16(gA + k0, lA0);
    gl_lds16(gA + 16 * DIM + k0, lA1);
    gl_lds16(gB + k0, lB0);
    gl_lds16(gB + 16 * DIM + k0, lB1);
    __syncthreads();                              // drains vmcnt -> LDS ready
    bf16x8 av[4], bv[4];
#pragma unroll
    for (int m = 0; m < 4; ++m) av[m] = *(const bf16x8*)&lds[aoff + m * 512];
#pragma unroll
    for (int n = 0; n < 4; ++n) bv[n] = *(const bf16x8*)&lds[boff + n * 512];
#pragma unroll
    for (int m = 0; m < 4; ++m)
#pragma unroll
      for (int n = 0; n < 4; ++n)
        acc[m][n] = __builtin_amdgcn_mfma_f32_16x16x32_bf16(av[m], bv[n], acc[m][n], 0, 0, 0);
    __syncthreads();
  }

  const bool act = (nBase >= DIM);                // f/r blocks -> sigmoid
#pragma unroll
  for (int m = 0; m < 4; ++m) {
    const int row0 = mBase + wm * 64 + m * 16 + lk * 4;
#pragma unroll
    for (int n = 0; n < 4; ++n) {
      const int col = nBase + wn * 64 + n * 16 + lr;
#pragma unroll
      for (int j = 0; j < 4; ++j) {
        float v = acc[m][n][j];
        if (act) v = 1.f / (1.f + __expf(-v));
        C[(size_t)(row0 + j) * N3 + col] = f2b(v);
      }
    }
  }
}

// ---------------- K1 fallback: f32-input reg-staged GEMM (round-1, validated) --
__global__ __launch_bounds__(256) void k_gemm_reg(const float* __restrict__ A,
                                                  const float* __restrict__ B,
                                                  u16* __restrict__ C) {
  __shared__ u16 lds[8192];
  const int tid  = threadIdx.x;
  const int lane = tid & 63;
  const int wid  = tid >> 6;
  const int wm = wid >> 1, wn = wid & 1;
  const int lr = lane & 15, lk = lane >> 4;
  const int mBase = blockIdx.y << 7;
  const int nBase = blockIdx.x << 7;

  f32x4 acc[4][4] = {};
  const int aoff = (wm * 64 + lr) * 32 + lk * 8;
  const int boff = 4096 + (wn * 64 + lr) * 32 + lk * 8;

  for (int k0 = 0; k0 < DIM; k0 += 32) {
#pragma unroll
    for (int q = 0; q < 4; ++q) {
      const int i  = q * 256 + tid;
      const int rr = i >> 3;
      const int cc = (i & 7) << 2;
      float4 va = *(const float4*)(A + (size_t)(mBase + rr) * DIM + k0 + cc);
      float4 vb = *(const float4*)(B + (size_t)(nBase + rr) * DIM + k0 + cc);
      uint2 pa; pa.x = pk2(va.x, va.y); pa.y = pk2(va.z, va.w);
      uint2 pb; pb.x = pk2(vb.x, vb.y); pb.y = pk2(vb.z, vb.w);
      *(uint2*)&lds[rr * 32 + cc] = pa;
      *(uint2*)&lds[4096 + rr * 32 + cc] = pb;
    }
    __syncthreads();
    bf16x8 av[4], bv[4];
#pragma unroll
    for (int m = 0; m < 4; ++m) av[m] = *(const bf16x8*)&lds[aoff + m * 512];
#pragma unroll
    for (int n = 0; n < 4; ++n) bv[n] = *(const bf16x8*)&lds[boff + n * 512];
#pragma unroll
    for (int m = 0; m < 4; ++m)
#pragma unroll
      for (int n = 0; n < 4; ++n)
        acc[m][n] = __builtin_amdgcn_mfma_f32_16x16x32_bf16(av[m], bv[n], acc[m][n], 0, 0, 0);
    __syncthreads();
  }

  const bool act = (nBase >= DIM);
#pragma unroll
  for (int m = 0; m < 4; ++m) {
    const int row0 = mBase + wm * 64 + m * 16 + lk * 4;
#pragma unroll
    for (int n = 0; n < 4; ++n) {
      const int col = nBase + wn * 64 + n * 16 + lr;
#pragma unroll
      for (int j = 0; j < 4; ++j) {
        float v = acc[m][n][j];
        if (act) v = 1.f / (1.f + __expf(-v));
        C[(size_t)(row0 + j) * N3 + col] = f2b(v);
      }
    }
  }
}

// ---------------- K2: chunk-local affine coefficients --------------------------
__global__ void k_scanA(const u16* __restrict__ ufr, float* __restrict__ P,
                        float* __restrict__ V) {
  int g = blockIdx.x * 256 + threadIdx.x;
  int j = g >> 13;
  int chain = g & (NCHAIN - 1);
  int b = chain >> 10;
  int d = chain & (DIM - 1);
  const u16* p = ufr + (size_t)((j * LCHUNK) * BATCH + b) * N3 + d;
  float prod = 1.f, v = 0.f;
  for (int t = 0; t < LCHUNK; ++t) {
    float u = b2f(p[0]);
    float f = b2f(p[DIM]);
    v = f * v + (1.f - f) * u;
    prod *= f;
    p += BATCH * N3;
  }
  P[g] = prod; V[g] = v;
}

// ---------------- K3: sequential combine over chunks ---------------------------
__global__ void k_scanB(const float* __restrict__ c0, const float* __restrict__ P,
                        const float* __restrict__ V, float* __restrict__ S,
                        float* __restrict__ lastc) {
  int chain = blockIdx.x * 256 + threadIdx.x;
  float c = c0[chain];
  for (int j = 0; j < NCHUNK; ++j) {
    S[j * NCHAIN + chain] = c;
    c = P[j * NCHAIN + chain] * c + V[j * NCHAIN + chain];
  }
  lastc[chain] = c;
}

// ---------------- K4: fused replay + hs + gelu + LayerNorm ---------------------
__global__ __launch_bounds__(1024) void k_scanln(const u16* __restrict__ ufr,
                                                 const float* __restrict__ S,
                                                 const float* __restrict__ x,
                                                 const float* __restrict__ lnw,
                                                 const float* __restrict__ lnb,
                                                 float* __restrict__ out) {
  const int j = blockIdx.x >> 3;
  const int b = blockIdx.x & 7;
  const int d = threadIdx.x;
  const int lane = d & 63, wid = d >> 6;

  float c = S[j * NCHAIN + b * DIM + d];
  const float wgt = lnw[d];
  const float bia = lnb[d];

  const u16*   pu = ufr + (size_t)((j * LCHUNK) * BATCH + b) * N3 + d;
  const float* px = x   + (size_t)((j * LCHUNK) * BATCH + b) * DIM + d;
  float*       po = out + (size_t)((j * LCHUNK) * BATCH + b) * DIM + d;

  __shared__ float red1[16], red2[16];

  for (int t = 0; t < LCHUNK; ++t) {
    float u = b2f(pu[0]);
    float f = b2f(pu[DIM]);
    float r = b2f(pu[2 * DIM]);
    c = f * c + (1.f - f) * u;
    float xx = *px;
    float hs = r * tanhf(c) + (1.f - r) * xx;
    float g  = 0.5f * hs * (1.f + erff(hs * 0.70710678118654752f));

    float s1 = g, s2 = g * g;
#pragma unroll
    for (int off = 32; off > 0; off >>= 1) {
      s1 += __shfl_down(s1, off, 64);
      s2 += __shfl_down(s2, off, 64);
    }
    if (lane == 0) { red1[wid] = s1; red2[wid] = s2; }
    __syncthreads();
    float S1 = 0.f, S2 = 0.f;
#pragma unroll
    for (int w = 0; w < 16; ++w) { S1 += red1[w]; S2 += red2[w]; }
    float mu  = S1 * (1.f / DIM);
    float var = S2 * (1.f / DIM) - mu * mu;
    float inv = rsqrtf(var + 1e-5f);
    *po = (g - mu) * inv * wgt + bia;
    __syncthreads();

    pu += BATCH * N3;
    px += BATCH * DIM;
    po += BATCH * DIM;
  }
}

extern "C" void kernel_launch(void* const* d_in, const int* in_sizes, int n_in,
                              void* d_out, int out_size, void* d_ws, size_t ws_size,
                              hipStream_t stream) {
  (void)in_sizes; (void)n_in; (void)out_size;
  const float* x   = (const float*)d_in[0];
  const float* c0  = (const float*)d_in[1];
  const float* W   = (const float*)d_in[2];
  const float* lnw = (const float*)d_in[3];
  const float* lnb = (const float*)d_in[4];
  float* out   = (float*)d_out;                   // (L,B,D) f32
  float* lastc = out + (size_t)ROWS * DIM;        // (B,D)   f32

  char* ws = (char*)d_ws;
  dim3 g1(N3 / 128, ROWS / 128);

  u16* ufr; float *P, *V, *S;
  const size_t FULL_NEED = 143654912;             // xb+wb+ufr+P+V+S
  if (ws_size >= FULL_NEED) {
    // fast path: pre-convert + global_load_lds GEMM
    u16* xb = (u16*)ws;                           // 33,554,432
    u16* wb = (u16*)(ws + 33554432);              //  6,291,456
    ufr = (u16*)(ws + 39845888);                  // 100,663,296
    P   = (float*)(ws + 140509184);
    V   = (float*)(ws + 141557760);
    S   = (float*)(ws + 142606336);
    k_convert<<<2048, 256, 0, stream>>>(x, W, xb, wb);
    k_gemm_lds<<<g1, 256, 0, stream>>>(xb, wb, ufr);
  } else {
    // fallback: round-1 validated reg-staged GEMM, 103.8 MB scratch
    ufr = (u16*)ws;
    P   = (float*)(ws + 100663296);
    V   = (float*)(ws + 101711872);
    S   = (float*)(ws + 102760448);
    k_gemm_reg<<<g1, 256, 0, stream>>>(x, W, ufr);
  }

  k_scanA<<<(NCHUNK * NCHAIN) / 256, 256, 0, stream>>>(ufr, P, V);
  k_scanB<<<NCHAIN / 256, 256, 0, stream>>>(c0, P, V, S, lastc);
  k_scanln<<<NCHUNK * BATCH, 1024, 0, stream>>>(ufr, S, x, lnw, lnb, out);
}

// Round 4
// 285.505 us; speedup vs baseline: 1.1173x; 1.1173x over previous
//
#include <hip/hip_runtime.h>

typedef unsigned short u16;
typedef unsigned int   u32;
typedef __attribute__((ext_vector_type(8))) __bf16 bf16x8;
typedef __attribute__((ext_vector_type(4))) float  f32x4;

#define L_SEQ  2048
#define BATCH  8
#define DIM    1024
#define ROWS   (L_SEQ*BATCH)     /* 16384 */
#define N3     (3*DIM)           /* 3072  */
#define NCHUNK 32
#define LCHUNK (L_SEQ/NCHUNK)    /* 64    */
#define NCHAIN (BATCH*DIM)       /* 8192  */

__device__ __forceinline__ float b2f(u16 h) {
  return __builtin_bit_cast(float, (u32)h << 16);
}
__device__ __forceinline__ u32 pk2(float a, float b) {   // pack 2 f32 -> 2 bf16 RNE
  u32 r;
  asm("v_cvt_pk_bf16_f32 %0, %1, %2" : "=v"(r) : "v"(a), "v"(b));
  return r;
}
__device__ __forceinline__ u16 f2b(float f) {
  u32 u = __builtin_bit_cast(u32, f);
  return (u16)((u + 0x7fffu + ((u >> 16) & 1u)) >> 16);
}

// ---------------- K0: convert x and W f32 -> bf16 ------------------------------
__global__ void k_convert(const float* __restrict__ x, const float* __restrict__ W,
                          u16* __restrict__ xb, u16* __restrict__ wb) {
  const int NX4 = (ROWS * DIM) / 4;
  const int NW4 = (N3 * DIM) / 4;
  int i = blockIdx.x * blockDim.x + threadIdx.x;
  const int stride = gridDim.x * blockDim.x;
  for (; i < NX4 + NW4; i += stride) {
    const float4* s; u16* d; int j;
    if (i < NX4) { s = (const float4*)x; d = xb; j = i; }
    else         { s = (const float4*)W; d = wb; j = i - NX4; }
    float4 v = s[j];
    uint2 o; o.x = pk2(v.x, v.y); o.y = pk2(v.z, v.w);
    *(uint2*)(d + 4 * (size_t)j) = o;
  }
}

// ---------------- K1: 256x256-tile bf16 GEMM, 3-slot ring, counted vmcnt -------
__device__ __forceinline__ void gl_lds16(const u16* g, u16* l) {
  __builtin_amdgcn_global_load_lds((const __attribute__((address_space(1))) void*)g,
                                   (__attribute__((address_space(3))) void*)l,
                                   16, 0, 0);
}

__global__ __launch_bounds__(512, 2) void k_gemm256(const u16* __restrict__ A,  // ROWS x DIM bf16
                                                    const u16* __restrict__ B,  // N3 x DIM bf16
                                                    u16* __restrict__ C) {      // ROWS x N3 bf16
  // LDS: A slots s*8192 u16 (16 KiB each, s=0..2); B slots 24576 + s*8192
  __shared__ u16 lds[49152];                      // 96 KiB
  const int tid  = threadIdx.x;
  const int lane = tid & 63;
  const int wid  = tid >> 6;                      // 8 waves: 2 (M) x 4 (N)
  const int wm = wid >> 2, wn = wid & 3;
  const int lr = lane & 15, lk = lane >> 4;

  // XCD-aware swizzle (768 = 8 * 96), then column-major tile order:
  // each XCD covers ~2 consecutive N-panels (B-panels stay L2-resident).
  const int bid = blockIdx.x;
  const int sid = (bid & 7) * 96 + (bid >> 3);
  const int bx = sid >> 6;                        // 0..11  (N tile)
  const int by = sid & 63;                        // 0..63  (M tile)
  const int mBase = by << 8;
  const int nBase = bx << 8;

  // staging map: load q covers i = q*512+tid; row = i>>2, k-slot = i&3
  const int i0 = tid, i1 = 512 + tid;
  const u16* gA0 = A + (size_t)(mBase + (i0 >> 2)) * DIM + ((i0 & 3) << 3);
  const u16* gA1 = A + (size_t)(mBase + (i1 >> 2)) * DIM + ((i1 & 3) << 3);
  const u16* gB0 = B + (size_t)(nBase + (i0 >> 2)) * DIM + ((i0 & 3) << 3);
  const u16* gB1 = B + (size_t)(nBase + (i1 >> 2)) * DIM + ((i1 & 3) << 3);
  u16* lA0 = &lds[i0 * 8];                        // byte addr = wave_base + lane*16  (linear)
  u16* lA1 = &lds[i1 * 8];
  u16* lB0 = &lds[24576 + i0 * 8];
  u16* lB1 = &lds[24576 + i1 * 8];

#define STAGE_A(T, S) { gl_lds16(gA0 + (T) * 32, lA0 + (S) * 8192); \
                        gl_lds16(gA1 + (T) * 32, lA1 + (S) * 8192); }
#define STAGE_B(T, S) { gl_lds16(gB0 + (T) * 32, lB0 + (S) * 8192); \
                        gl_lds16(gB1 + (T) * 32, lB1 + (S) * 8192); }

  const int aBase = (wm * 128 + lr) * 32 + lk * 8;
  const int bBase = (wn * 64 + lr) * 32 + lk * 8;

  f32x4 acc[8][4] = {};

  // prologue: stage tiles 0,1 -> slots 0,1; wait for tile 0
  STAGE_A(0, 0) STAGE_B(0, 0)
  STAGE_A(1, 1) STAGE_B(1, 1)
  asm volatile("s_waitcnt vmcnt(4)" ::: "memory");
  asm volatile("s_barrier" ::: "memory");

  int s = 0;
  for (int t = 0; t < 32; ++t) {
    const u16* bufA = &lds[s * 8192];
    const u16* bufB = &lds[24576 + s * 8192];
    const int s2 = (s + 2 >= 3) ? s - 1 : s + 2;

    // ---- phase 0: read B-frags + A-frags (fm 0..3), stage A(t+2), MFMA ----
    bf16x8 bv[4], av0[4];
#pragma unroll
    for (int n = 0; n < 4; ++n) bv[n] = *(const bf16x8*)&bufB[bBase + n * 512];
#pragma unroll
    for (int m = 0; m < 4; ++m) av0[m] = *(const bf16x8*)&bufA[aBase + m * 512];
    if (t < 30) STAGE_A(t + 2, s2)
    __builtin_amdgcn_s_setprio(1);
#pragma unroll
    for (int m = 0; m < 4; ++m)
#pragma unroll
      for (int n = 0; n < 4; ++n)
        acc[m][n] = __builtin_amdgcn_mfma_f32_16x16x32_bf16(av0[m], bv[n], acc[m][n], 0, 0, 0);
    __builtin_amdgcn_s_setprio(0);
    asm volatile("s_barrier" ::: "memory");

    // ---- phase 1: read A-frags (fm 4..7), stage B(t+2), counted vmcnt, MFMA ----
    bf16x8 av1[4];
#pragma unroll
    for (int m = 0; m < 4; ++m) av1[m] = *(const bf16x8*)&bufA[aBase + 2048 + m * 512];
    if (t < 30) STAGE_B(t + 2, s2)
    if (t < 30) { asm volatile("s_waitcnt vmcnt(4)" ::: "memory"); }
    else        { asm volatile("s_waitcnt vmcnt(0)" ::: "memory"); }
    __builtin_amdgcn_s_setprio(1);
#pragma unroll
    for (int m = 0; m < 4; ++m)
#pragma unroll
      for (int n = 0; n < 4; ++n)
        acc[4 + m][n] = __builtin_amdgcn_mfma_f32_16x16x32_bf16(av1[m], bv[n], acc[4 + m][n], 0, 0, 0);
    __builtin_amdgcn_s_setprio(0);
    asm volatile("s_barrier" ::: "memory");

    s = (s + 1 >= 3) ? 0 : s + 1;
  }
#undef STAGE_A
#undef STAGE_B

  const bool act = (nBase >= DIM);                // f/r blocks -> sigmoid
#pragma unroll
  for (int m = 0; m < 8; ++m) {
    const int row0 = mBase + wm * 128 + m * 16 + lk * 4;
#pragma unroll
    for (int n = 0; n < 4; ++n) {
      const int col = nBase + wn * 64 + n * 16 + lr;
#pragma unroll
      for (int j = 0; j < 4; ++j) {
        float v = acc[m][n][j];
        if (act) v = 1.f / (1.f + __expf(-v));
        C[(size_t)(row0 + j) * N3 + col] = f2b(v);
      }
    }
  }
}

// ---------------- K1 fallback: f32-input reg-staged GEMM (validated r1) --------
__global__ __launch_bounds__(256) void k_gemm_reg(const float* __restrict__ A,
                                                  const float* __restrict__ B,
                                                  u16* __restrict__ C) {
  __shared__ u16 lds[8192];
  const int tid  = threadIdx.x;
  const int lane = tid & 63;
  const int wid  = tid >> 6;
  const int wm = wid >> 1, wn = wid & 1;
  const int lr = lane & 15, lk = lane >> 4;
  const int mBase = blockIdx.y << 7;
  const int nBase = blockIdx.x << 7;

  f32x4 acc[4][4] = {};
  const int aoff = (wm * 64 + lr) * 32 + lk * 8;
  const int boff = 4096 + (wn * 64 + lr) * 32 + lk * 8;

  for (int k0 = 0; k0 < DIM; k0 += 32) {
#pragma unroll
    for (int q = 0; q < 4; ++q) {
      const int i  = q * 256 + tid;
      const int rr = i >> 3;
      const int cc = (i & 7) << 2;
      float4 va = *(const float4*)(A + (size_t)(mBase + rr) * DIM + k0 + cc);
      float4 vb = *(const float4*)(B + (size_t)(nBase + rr) * DIM + k0 + cc);
      uint2 pa; pa.x = pk2(va.x, va.y); pa.y = pk2(va.z, va.w);
      uint2 pb; pb.x = pk2(vb.x, vb.y); pb.y = pk2(vb.z, vb.w);
      *(uint2*)&lds[rr * 32 + cc] = pa;
      *(uint2*)&lds[4096 + rr * 32 + cc] = pb;
    }
    __syncthreads();
    bf16x8 av[4], bv[4];
#pragma unroll
    for (int m = 0; m < 4; ++m) av[m] = *(const bf16x8*)&lds[aoff + m * 512];
#pragma unroll
    for (int n = 0; n < 4; ++n) bv[n] = *(const bf16x8*)&lds[boff + n * 512];
#pragma unroll
    for (int m = 0; m < 4; ++m)
#pragma unroll
      for (int n = 0; n < 4; ++n)
        acc[m][n] = __builtin_amdgcn_mfma_f32_16x16x32_bf16(av[m], bv[n], acc[m][n], 0, 0, 0);
    __syncthreads();
  }

  const bool act = (nBase >= DIM);
#pragma unroll
  for (int m = 0; m < 4; ++m) {
    const int row0 = mBase + wm * 64 + m * 16 + lk * 4;
#pragma unroll
    for (int n = 0; n < 4; ++n) {
      const int col = nBase + wn * 64 + n * 16 + lr;
#pragma unroll
      for (int j = 0; j < 4; ++j) {
        float v = acc[m][n][j];
        if (act) v = 1.f / (1.f + __expf(-v));
        C[(size_t)(row0 + j) * N3 + col] = f2b(v);
      }
    }
  }
}

// ---------------- K2: chunk-local affine coefficients --------------------------
__global__ void k_scanA(const u16* __restrict__ ufr, float* __restrict__ P,
                        float* __restrict__ V) {
  int g = blockIdx.x * 256 + threadIdx.x;
  int j = g >> 13;
  int chain = g & (NCHAIN - 1);
  int b = chain >> 10;
  int d = chain & (DIM - 1);
  const u16* p = ufr + (size_t)((j * LCHUNK) * BATCH + b) * N3 + d;
  float prod = 1.f, v = 0.f;
  for (int t = 0; t < LCHUNK; ++t) {
    float u = b2f(p[0]);
    float f = b2f(p[DIM]);
    v = f * v + (1.f - f) * u;
    prod *= f;
    p += BATCH * N3;
  }
  P[g] = prod; V[g] = v;
}

// ---------------- K3: sequential combine over chunks ---------------------------
__global__ void k_scanB(const float* __restrict__ c0, const float* __restrict__ P,
                        const float* __restrict__ V, float* __restrict__ S,
                        float* __restrict__ lastc) {
  int chain = blockIdx.x * 256 + threadIdx.x;
  float c = c0[chain];
  for (int j = 0; j < NCHUNK; ++j) {
    S[j * NCHAIN + chain] = c;
    c = P[j * NCHAIN + chain] * c + V[j * NCHAIN + chain];
  }
  lastc[chain] = c;
}

// ---------------- K4: fused replay + hs + gelu + LayerNorm ---------------------
__global__ __launch_bounds__(1024) void k_scanln(const u16* __restrict__ ufr,
                                                 const float* __restrict__ S,
                                                 const float* __restrict__ x,
                                                 const float* __restrict__ lnw,
                                                 const float* __restrict__ lnb,
                                                 float* __restrict__ out) {
  const int j = blockIdx.x >> 3;
  const int b = blockIdx.x & 7;
  const int d = threadIdx.x;
  const int lane = d & 63, wid = d >> 6;

  float c = S[j * NCHAIN + b * DIM + d];
  const float wgt = lnw[d];
  const float bia = lnb[d];

  const u16*   pu = ufr + (size_t)((j * LCHUNK) * BATCH + b) * N3 + d;
  const float* px = x   + (size_t)((j * LCHUNK) * BATCH + b) * DIM + d;
  float*       po = out + (size_t)((j * LCHUNK) * BATCH + b) * DIM + d;

  __shared__ float red1[16], red2[16];

  for (int t = 0; t < LCHUNK; ++t) {
    float u = b2f(pu[0]);
    float f = b2f(pu[DIM]);
    float r = b2f(pu[2 * DIM]);
    c = f * c + (1.f - f) * u;
    float xx = *px;
    float hs = r * tanhf(c) + (1.f - r) * xx;
    float g  = 0.5f * hs * (1.f + erff(hs * 0.70710678118654752f));

    float s1 = g, s2 = g * g;
#pragma unroll
    for (int off = 32; off > 0; off >>= 1) {
      s1 += __shfl_down(s1, off, 64);
      s2 += __shfl_down(s2, off, 64);
    }
    if (lane == 0) { red1[wid] = s1; red2[wid] = s2; }
    __syncthreads();
    float S1 = 0.f, S2 = 0.f;
#pragma unroll
    for (int w = 0; w < 16; ++w) { S1 += red1[w]; S2 += red2[w]; }
    float mu  = S1 * (1.f / DIM);
    float var = S2 * (1.f / DIM) - mu * mu;
    float inv = rsqrtf(var + 1e-5f);
    *po = (g - mu) * inv * wgt + bia;
    __syncthreads();

    pu += BATCH * N3;
    px += BATCH * DIM;
    po += BATCH * DIM;
  }
}

extern "C" void kernel_launch(void* const* d_in, const int* in_sizes, int n_in,
                              void* d_out, int out_size, void* d_ws, size_t ws_size,
                              hipStream_t stream) {
  (void)in_sizes; (void)n_in; (void)out_size;
  const float* x   = (const float*)d_in[0];
  const float* c0  = (const float*)d_in[1];
  const float* W   = (const float*)d_in[2];
  const float* lnw = (const float*)d_in[3];
  const float* lnb = (const float*)d_in[4];
  float* out   = (float*)d_out;                   // (L,B,D) f32
  float* lastc = out + (size_t)ROWS * DIM;        // (B,D)   f32

  char* ws = (char*)d_ws;

  u16* ufr; float *P, *V, *S;
  const size_t FULL_NEED = 143654912;
  if (ws_size >= FULL_NEED) {
    u16* xb = (u16*)ws;
    u16* wb = (u16*)(ws + 33554432);
    ufr = (u16*)(ws + 39845888);
    P   = (float*)(ws + 140509184);
    V   = (float*)(ws + 141557760);
    S   = (float*)(ws + 142606336);
    k_convert<<<2048, 256, 0, stream>>>(x, W, xb, wb);
    k_gemm256<<<768, 512, 0, stream>>>(xb, wb, ufr);
  } else {
    ufr = (u16*)ws;
    P   = (float*)(ws + 100663296);
    V   = (float*)(ws + 101711872);
    S   = (float*)(ws + 102760448);
    dim3 g1(N3 / 128, ROWS / 128);
    k_gemm_reg<<<g1, 256, 0, stream>>>(x, W, ufr);
  }

  k_scanA<<<(NCHUNK * NCHAIN) / 256, 256, 0, stream>>>(ufr, P, V);
  k_scanB<<<NCHAIN / 256, 256, 0, stream>>>(c0, P, V, S, lastc);
  k_scanln<<<NCHUNK * BATCH, 1024, 0, stream>>>(ufr, S, x, lnw, lnb, out);
}

// Round 5
// 258.304 us; speedup vs baseline: 1.2349x; 1.1053x over previous
//
#include <hip/hip_runtime.h>

typedef unsigned short u16;
typedef unsigned int   u32;
typedef __attribute__((ext_vector_type(8))) __bf16 bf16x8;
typedef __attribute__((ext_vector_type(4))) float  f32x4;

#define L_SEQ  2048
#define BATCH  8
#define DIM    1024
#define ROWS   16384
#define N3     3072
#define NCHUNK 32
#define LCHUNK 64
#define NCHAIN 8192

__device__ __forceinline__ float b2f(u16 h) {
  return __builtin_bit_cast(float, (u32)h << 16);
}
__device__ __forceinline__ u32 pk2(float a, float b) {
  u32 r;
  asm("v_cvt_pk_bf16_f32 %0, %1, %2" : "=v"(r) : "v"(a), "v"(b));
  return r;
}
__device__ __forceinline__ u16 f2b(float f) {
  u32 u = __builtin_bit_cast(u32, f);
  return (u16)((u + 0x7fffu + ((u >> 16) & 1u)) >> 16);
}
__device__ __forceinline__ f32x4 mf(bf16x8 a, bf16x8 b, f32x4 c) {
  return __builtin_amdgcn_mfma_f32_16x16x32_bf16(a, b, c, 0, 0, 0);
}

// ---------------- K0: pack x -> apk, W -> wpk in MFMA-frag order ---------------
// A chunk ca = ((mt*32+t)*8+fg)*64+lane : 8 u16 = x[mt*128+fg*16+(lane&15)][t*32+(lane>>4)*8 ..+8]
// B chunk cb = ((nt*32+t)*16+c)*64+lane : 8 u16 = W[nt*256+c*16+(lane&15)][t*32+(lane>>4)*8 ..+8]
__global__ void k_pack(const float* __restrict__ x, const float* __restrict__ W,
                       u16* __restrict__ apk, u16* __restrict__ wpk) {
  const int NA = 128 * 32 * 8 * 64;   // 2097152
  const int NB = 12 * 32 * 16 * 64;   // 393216
  int i = blockIdx.x * 256 + threadIdx.x;
  const int stride = gridDim.x * 256;
  for (; i < NA + NB; i += stride) {
    const float* src; u16* dst;
    if (i < NA) {
      int lane = i & 63, fg = (i >> 6) & 7, t = (i >> 9) & 31, mt = i >> 14;
      int row = mt * 128 + fg * 16 + (lane & 15);
      int k   = t * 32 + (lane >> 4) * 8;
      src = x + (size_t)row * DIM + k;
      dst = apk + (size_t)i * 8;
    } else {
      int j = i - NA;
      int lane = j & 63, c = (j >> 6) & 15, t = (j >> 10) & 31, nt = j >> 15;
      int col = nt * 256 + c * 16 + (lane & 15);
      int k   = t * 32 + (lane >> 4) * 8;
      src = W + (size_t)col * DIM + k;
      dst = wpk + (size_t)j * 8;
    }
    float4 v0 = *(const float4*)src;
    float4 v1 = *(const float4*)(src + 4);
    uint4 o;
    o.x = pk2(v0.x, v0.y); o.y = pk2(v0.z, v0.w);
    o.z = pk2(v1.x, v1.y); o.w = pk2(v1.z, v1.w);
    *(uint4*)dst = o;
  }
}

// ---------------- K1: GEMM 128x256 tile, A via 3-slot gl_lds ring, B direct ----
__device__ __forceinline__ void gl_lds16(const u16* g, u16* l) {
  __builtin_amdgcn_global_load_lds((const __attribute__((address_space(1))) void*)g,
                                   (__attribute__((address_space(3))) void*)l,
                                   16, 0, 0);
}

__global__ __launch_bounds__(512, 4) void k_gemm_v3(const u16* __restrict__ apk,
                                                    const u16* __restrict__ wpk,
                                                    u16* __restrict__ C) {
  __shared__ u16 lds[12288];                      // 3 slots x 8 KB (A tile 128x32)
  const int tid  = threadIdx.x;
  const int lane = tid & 63;
  const int wid  = tid >> 6;                      // 8 waves: wm 0..1, wn 0..3
  const int wm = wid >> 2, wn = wid & 3;
  const int lr = lane & 15, lk = lane >> 4;

  const int bid = blockIdx.x;                     // 1536 = 8 XCD * 192
  const int xcd = bid & 7;
  const int r   = bid >> 3;                       // 0..191
  const int byl = r / 12;                         // 0..15
  const int bx  = r - byl * 12;                   // 0..11  N-panel
  const int by  = xcd * 16 + byl;                 // 0..127 M-tile

  // A stage src: wave wid stages frag-group fg=wid; 1 KB per t
  const u16* srcA = apk + ((((size_t)by * 32) * 8 + wid) * 64 + lane) * 8;
  // B direct: frag (wn,n) at t: chunk ((bx*32+t)*16 + wn*4+n)*64+lane
  const u16* srcB = wpk + ((((size_t)bx * 32) * 16 + wn * 4) * 64 + lane) * 8;

  u16* d0 = &lds[wid * 512 + lane * 8];
  u16* d1 = d0 + 4096;
  u16* d2 = d0 + 8192;
  const u16* ldsA = &lds[wm * 2048 + lane * 8];

  f32x4 acc[4][4] = {};

  // prologue: stage t=0 -> slot0, t=1 -> slot1
  gl_lds16(srcA, d0);
  gl_lds16(srcA + 4096, d1);
  asm volatile("s_waitcnt vmcnt(1)" ::: "memory");
  asm volatile("s_barrier" ::: "memory");

#define GBODY(T, S, DN) {                                                      \
    if ((T) < 30) gl_lds16(srcA + (size_t)((T) + 2) * 4096, DN);               \
    const u16* rb_ = ldsA + (S) * 4096;                                        \
    bf16x8 av0 = *(const bf16x8*)(rb_);                                        \
    bf16x8 av1 = *(const bf16x8*)(rb_ + 512);                                  \
    bf16x8 av2 = *(const bf16x8*)(rb_ + 1024);                                 \
    bf16x8 av3 = *(const bf16x8*)(rb_ + 1536);                                 \
    const u16* gb_ = srcB + (size_t)(T) * 8192;                                \
    bf16x8 bv0 = *(const bf16x8*)(gb_);                                        \
    bf16x8 bv1 = *(const bf16x8*)(gb_ + 512);                                  \
    bf16x8 bv2 = *(const bf16x8*)(gb_ + 1024);                                 \
    bf16x8 bv3 = *(const bf16x8*)(gb_ + 1536);                                 \
    __builtin_amdgcn_s_setprio(1);                                             \
    acc[0][0] = mf(av0, bv0, acc[0][0]); acc[0][1] = mf(av0, bv1, acc[0][1]);  \
    acc[0][2] = mf(av0, bv2, acc[0][2]); acc[0][3] = mf(av0, bv3, acc[0][3]);  \
    acc[1][0] = mf(av1, bv0, acc[1][0]); acc[1][1] = mf(av1, bv1, acc[1][1]);  \
    acc[1][2] = mf(av1, bv2, acc[1][2]); acc[1][3] = mf(av1, bv3, acc[1][3]);  \
    acc[2][0] = mf(av2, bv0, acc[2][0]); acc[2][1] = mf(av2, bv1, acc[2][1]);  \
    acc[2][2] = mf(av2, bv2, acc[2][2]); acc[2][3] = mf(av2, bv3, acc[2][3]);  \
    acc[3][0] = mf(av3, bv0, acc[3][0]); acc[3][1] = mf(av3, bv1, acc[3][1]);  \
    acc[3][2] = mf(av3, bv2, acc[3][2]); acc[3][3] = mf(av3, bv3, acc[3][3]);  \
    __builtin_amdgcn_s_setprio(0);                                             \
    if ((T) < 30)       asm volatile("s_waitcnt vmcnt(1)" ::: "memory");       \
    else if ((T) == 30) asm volatile("s_waitcnt vmcnt(0)" ::: "memory");       \
    if ((T) < 31)       asm volatile("s_barrier" ::: "memory");                \
  }

  for (int t3 = 0; t3 < 30; t3 += 3) {
    GBODY(t3 + 0, 0, d2)
    GBODY(t3 + 1, 1, d0)
    GBODY(t3 + 2, 2, d1)
  }
  GBODY(30, 0, d2)
  GBODY(31, 1, d0)
#undef GBODY

  const bool act = (bx >= 4);                     // f/r panels -> sigmoid
#pragma unroll
  for (int m = 0; m < 4; ++m) {
    const int row0 = by * 128 + wm * 64 + m * 16 + lk * 4;
#pragma unroll
    for (int n = 0; n < 4; ++n) {
      const int col = bx * 256 + wn * 64 + n * 16 + lr;
#pragma unroll
      for (int j = 0; j < 4; ++j) {
        float v = acc[m][n][j];
        if (act) v = 1.f / (1.f + __expf(-v));
        C[(size_t)(row0 + j) * N3 + col] = f2b(v);
      }
    }
  }
}

// ---------------- K1 fallback: f32-input reg-staged GEMM (validated r1) --------
__global__ __launch_bounds__(256) void k_gemm_reg(const float* __restrict__ A,
                                                  const float* __restrict__ B,
                                                  u16* __restrict__ C) {
  __shared__ u16 lds[8192];
  const int tid  = threadIdx.x;
  const int lane = tid & 63;
  const int wid  = tid >> 6;
  const int wm = wid >> 1, wn = wid & 1;
  const int lr = lane & 15, lk = lane >> 4;
  const int mBase = blockIdx.y << 7;
  const int nBase = blockIdx.x << 7;

  f32x4 acc[4][4] = {};
  const int aoff = (wm * 64 + lr) * 32 + lk * 8;
  const int boff = 4096 + (wn * 64 + lr) * 32 + lk * 8;

  for (int k0 = 0; k0 < DIM; k0 += 32) {
#pragma unroll
    for (int q = 0; q < 4; ++q) {
      const int i  = q * 256 + tid;
      const int rr = i >> 3;
      const int cc = (i & 7) << 2;
      float4 va = *(const float4*)(A + (size_t)(mBase + rr) * DIM + k0 + cc);
      float4 vb = *(const float4*)(B + (size_t)(nBase + rr) * DIM + k0 + cc);
      uint2 pa; pa.x = pk2(va.x, va.y); pa.y = pk2(va.z, va.w);
      uint2 pb; pb.x = pk2(vb.x, vb.y); pb.y = pk2(vb.z, vb.w);
      *(uint2*)&lds[rr * 32 + cc] = pa;
      *(uint2*)&lds[4096 + rr * 32 + cc] = pb;
    }
    __syncthreads();
    bf16x8 av[4], bv[4];
#pragma unroll
    for (int m = 0; m < 4; ++m) av[m] = *(const bf16x8*)&lds[aoff + m * 512];
#pragma unroll
    for (int n = 0; n < 4; ++n) bv[n] = *(const bf16x8*)&lds[boff + n * 512];
#pragma unroll
    for (int m = 0; m < 4; ++m)
#pragma unroll
      for (int n = 0; n < 4; ++n)
        acc[m][n] = mf(av[m], bv[n], acc[m][n]);
    __syncthreads();
  }

  const bool act = (nBase >= DIM);
#pragma unroll
  for (int m = 0; m < 4; ++m) {
    const int row0 = mBase + wm * 64 + m * 16 + lk * 4;
#pragma unroll
    for (int n = 0; n < 4; ++n) {
      const int col = nBase + wn * 64 + n * 16 + lr;
#pragma unroll
      for (int j = 0; j < 4; ++j) {
        float v = acc[m][n][j];
        if (act) v = 1.f / (1.f + __expf(-v));
        C[(size_t)(row0 + j) * N3 + col] = f2b(v);
      }
    }
  }
}

// ---------------- K2: chunk-local affine coefficients --------------------------
__global__ void k_scanA(const u16* __restrict__ ufr, float* __restrict__ P,
                        float* __restrict__ V) {
  int g = blockIdx.x * 256 + threadIdx.x;
  int j = g >> 13;
  int chain = g & (NCHAIN - 1);
  int b = chain >> 10;
  int d = chain & (DIM - 1);
  const u16* p = ufr + (size_t)((j * LCHUNK) * BATCH + b) * N3 + d;
  float prod = 1.f, v = 0.f;
  for (int t = 0; t < LCHUNK; ++t) {
    float u = b2f(p[0]);
    float f = b2f(p[DIM]);
    v = f * v + (1.f - f) * u;
    prod *= f;
    p += BATCH * N3;
  }
  P[g] = prod; V[g] = v;
}

// ---------------- K3: sequential combine over chunks ---------------------------
__global__ void k_scanB(const float* __restrict__ c0, const float* __restrict__ P,
                        const float* __restrict__ V, float* __restrict__ S,
                        float* __restrict__ lastc) {
  int chain = blockIdx.x * 256 + threadIdx.x;
  float c = c0[chain];
  for (int j = 0; j < NCHUNK; ++j) {
    S[j * NCHAIN + chain] = c;
    c = P[j * NCHAIN + chain] * c + V[j * NCHAIN + chain];
  }
  lastc[chain] = c;
}

// ---------------- K4: fused replay + hs + gelu + LayerNorm (prefetched) --------
__global__ __launch_bounds__(1024) void k_scanln(const u16* __restrict__ ufr,
                                                 const float* __restrict__ S,
                                                 const float* __restrict__ x,
                                                 const float* __restrict__ lnw,
                                                 const float* __restrict__ lnb,
                                                 float* __restrict__ out) {
  const int j = blockIdx.x >> 3;
  const int b = blockIdx.x & 7;
  const int d = threadIdx.x;
  const int lane = d & 63, wid = d >> 6;

  float c = S[j * NCHAIN + b * DIM + d];
  const float wgt = lnw[d];
  const float bia = lnb[d];

  const u16*   pu = ufr + (size_t)((j * LCHUNK) * BATCH + b) * N3 + d;
  const float* px = x   + (size_t)((j * LCHUNK) * BATCH + b) * DIM + d;
  float*       po = out + (size_t)((j * LCHUNK) * BATCH + b) * DIM + d;

  __shared__ float red1[16], red2[16];

  // prefetch t=0
  u16 cu = pu[0], cf = pu[DIM], cr = pu[2 * DIM];
  float cx = *px;

  for (int t = 0; t < LCHUNK; ++t) {
    // issue t+1 loads early (latency hides under reduce barriers)
    const int adv = (t < LCHUNK - 1) ? 1 : 0;
    u16 nu = pu[(size_t)adv * BATCH * N3];
    u16 nf = pu[(size_t)adv * BATCH * N3 + DIM];
    u16 nr = pu[(size_t)adv * BATCH * N3 + 2 * DIM];
    float nx = px[(size_t)adv * BATCH * DIM];

    float u = b2f(cu), f = b2f(cf), rr = b2f(cr), xx = cx;
    c = f * c + (1.f - f) * u;
    float hs = rr * tanhf(c) + (1.f - rr) * xx;
    float g  = 0.5f * hs * (1.f + erff(hs * 0.70710678118654752f));

    float s1 = g, s2 = g * g;
#pragma unroll
    for (int off = 32; off > 0; off >>= 1) {
      s1 += __shfl_down(s1, off, 64);
      s2 += __shfl_down(s2, off, 64);
    }
    if (lane == 0) { red1[wid] = s1; red2[wid] = s2; }
    __syncthreads();
    float S1 = 0.f, S2 = 0.f;
#pragma unroll
    for (int w = 0; w < 16; ++w) { S1 += red1[w]; S2 += red2[w]; }
    float mu  = S1 * (1.f / DIM);
    float var = S2 * (1.f / DIM) - mu * mu;
    float inv = rsqrtf(var + 1e-5f);
    *po = (g - mu) * inv * wgt + bia;
    __syncthreads();

    cu = nu; cf = nf; cr = nr; cx = nx;
    pu += BATCH * N3;
    px += BATCH * DIM;
    po += BATCH * DIM;
  }
}

extern "C" void kernel_launch(void* const* d_in, const int* in_sizes, int n_in,
                              void* d_out, int out_size, void* d_ws, size_t ws_size,
                              hipStream_t stream) {
  (void)in_sizes; (void)n_in; (void)out_size;
  const float* x   = (const float*)d_in[0];
  const float* c0  = (const float*)d_in[1];
  const float* W   = (const float*)d_in[2];
  const float* lnw = (const float*)d_in[3];
  const float* lnb = (const float*)d_in[4];
  float* out   = (float*)d_out;                   // (L,B,D) f32
  float* lastc = out + (size_t)ROWS * DIM;        // (B,D)   f32

  char* ws = (char*)d_ws;

  u16* ufr; float *P, *V, *S;
  const size_t FULL_NEED = 143654912;
  if (ws_size >= FULL_NEED) {
    u16* apk = (u16*)ws;                          // 33,554,432 B
    u16* wpk = (u16*)(ws + 33554432);             //  6,291,456 B
    ufr = (u16*)(ws + 39845888);                  // 100,663,296 B
    P   = (float*)(ws + 140509184);
    V   = (float*)(ws + 141557760);
    S   = (float*)(ws + 142606336);
    k_pack<<<2048, 256, 0, stream>>>(x, W, apk, wpk);
    k_gemm_v3<<<1536, 512, 0, stream>>>(apk, wpk, ufr);
  } else {
    ufr = (u16*)ws;
    P   = (float*)(ws + 100663296);
    V   = (float*)(ws + 101711872);
    S   = (float*)(ws + 102760448);
    dim3 g1(N3 / 128, ROWS / 128);
    k_gemm_reg<<<g1, 256, 0, stream>>>(x, W, ufr);
  }

  k_scanA<<<(NCHUNK * NCHAIN) / 256, 256, 0, stream>>>(ufr, P, V);
  k_scanB<<<NCHAIN / 256, 256, 0, stream>>>(c0, P, V, S, lastc);
  k_scanln<<<NCHUNK * BATCH, 1024, 0, stream>>>(ufr, S, x, lnw, lnb, out);
}

// Round 6
// 229.178 us; speedup vs baseline: 1.3919x; 1.1271x over previous
//
#include <hip/hip_runtime.h>

typedef unsigned short u16;
typedef unsigned int   u32;
typedef __attribute__((ext_vector_type(8))) __bf16 bf16x8;
typedef __attribute__((ext_vector_type(4))) float  f32x4;

#define L_SEQ  2048
#define BATCH  8
#define DIM    1024
#define ROWS   16384
#define N3     3072
#define NCHUNK 64
#define LCHUNK 32
#define NCHAIN 8192

__device__ __forceinline__ float b2f(u16 h) {
  return __builtin_bit_cast(float, (u32)h << 16);
}
__device__ __forceinline__ u32 pk2(float a, float b) {
  u32 r;
  asm("v_cvt_pk_bf16_f32 %0, %1, %2" : "=v"(r) : "v"(a), "v"(b));
  return r;
}
__device__ __forceinline__ u16 f2b(float f) {
  u32 u = __builtin_bit_cast(u32, f);
  return (u16)((u + 0x7fffu + ((u >> 16) & 1u)) >> 16);
}
__device__ __forceinline__ f32x4 mf(bf16x8 a, bf16x8 b, f32x4 c) {
  return __builtin_amdgcn_mfma_f32_16x16x32_bf16(a, b, c, 0, 0, 0);
}

// ---------------- K0: pack x -> apk, W -> wpk in MFMA-frag order ---------------
__global__ void k_pack(const float* __restrict__ x, const float* __restrict__ W,
                       u16* __restrict__ apk, u16* __restrict__ wpk) {
  const int NA = 128 * 32 * 8 * 64;   // 2097152 chunks of 8 u16
  const int NB = 12 * 32 * 16 * 64;   // 393216
  int i = blockIdx.x * 256 + threadIdx.x;
  const int stride = gridDim.x * 256;
  for (; i < NA + NB; i += stride) {
    const float* src; u16* dst;
    if (i < NA) {
      int lane = i & 63, fg = (i >> 6) & 7, t = (i >> 9) & 31, mt = i >> 14;
      int row = mt * 128 + fg * 16 + (lane & 15);
      int k   = t * 32 + (lane >> 4) * 8;
      src = x + (size_t)row * DIM + k;
      dst = apk + (size_t)i * 8;
    } else {
      int j = i - NA;
      int lane = j & 63, c = (j >> 6) & 15, t = (j >> 10) & 31, nt = j >> 15;
      int col = nt * 256 + c * 16 + (lane & 15);
      int k   = t * 32 + (lane >> 4) * 8;
      src = W + (size_t)col * DIM + k;
      dst = wpk + (size_t)j * 8;
    }
    float4 v0 = *(const float4*)src;
    float4 v1 = *(const float4*)(src + 4);
    uint4 o;
    o.x = pk2(v0.x, v0.y); o.y = pk2(v0.z, v0.w);
    o.z = pk2(v1.x, v1.y); o.w = pk2(v1.z, v1.w);
    *(uint4*)dst = o;
  }
}

// ---------------- K1: GEMM, A 3-slot gl_lds ring, B reg-double-buffered --------
__device__ __forceinline__ void gl_lds16(const u16* g, u16* l) {
  __builtin_amdgcn_global_load_lds((const __attribute__((address_space(1))) void*)g,
                                   (__attribute__((address_space(3))) void*)l,
                                   16, 0, 0);
}

__global__ __launch_bounds__(512, 4) void k_gemm_v4(const u16* __restrict__ apk,
                                                    const u16* __restrict__ wpk,
                                                    u16* __restrict__ C) {
  __shared__ u16 lds[12288];                      // 3 slots x 8 KB (A tile 128x32)
  const int tid  = threadIdx.x;
  const int lane = tid & 63;
  const int wid  = tid >> 6;                      // 8 waves: wm 0..1, wn 0..3
  const int wm = wid >> 2, wn = wid & 3;
  const int lr = lane & 15, lk = lane >> 4;

  const int bid = blockIdx.x;                     // 1536 = 8 XCD * 192
  const int xcd = bid & 7;
  const int r   = bid >> 3;
  const int byl = r / 12;
  const int bx  = r - byl * 12;                   // N-panel (fast-varying: A reuse in L2)
  const int by  = xcd * 16 + byl;

  const u16* srcA = apk + ((((size_t)by * 32) * 8 + wid) * 64 + lane) * 8;
  const u16* srcB = wpk + ((((size_t)bx * 32) * 16 + wn * 4) * 64 + lane) * 8;

  u16* d0 = &lds[wid * 512 + lane * 8];
  u16* d1 = d0 + 4096;
  u16* d2 = d0 + 8192;
  const u16* ldsA = &lds[wm * 2048 + lane * 8];

  f32x4 acc[4][4] = {};
  bf16x8 A0, A1, A2, A3, B0, B1, B2, B3;          // two B-frag register sets

  // prologue: bv(0) -> set A; stage A-tiles 0,1
  {
    const u16* gb = srcB;
    A0 = *(const bf16x8*)(gb);
    A1 = *(const bf16x8*)(gb + 512);
    A2 = *(const bf16x8*)(gb + 1024);
    A3 = *(const bf16x8*)(gb + 1536);
  }
  __builtin_amdgcn_sched_barrier(0);
  gl_lds16(srcA, d0);
  gl_lds16(srcA + 4096, d1);
  asm volatile("s_waitcnt vmcnt(1)" ::: "memory");  // bv(0)+A(0) done, A(1) in flight
  asm volatile("s_barrier" ::: "memory");

  // WMODE: 0 = vmcnt(1)+barrier, 1 = vmcnt(0)+barrier, 2 = none
#define GBODY(T, RB, DN, U0,U1,U2,U3, L0,L1,L2,L3, LOADB, STAGEA, WMODE) {   \
    if (LOADB) {                                                             \
      const u16* gb_ = srcB + (size_t)((T) + 1) * 8192;                      \
      L0 = *(const bf16x8*)(gb_);                                            \
      L1 = *(const bf16x8*)(gb_ + 512);                                      \
      L2 = *(const bf16x8*)(gb_ + 1024);                                     \
      L3 = *(const bf16x8*)(gb_ + 1536);                                     \
    }                                                                        \
    __builtin_amdgcn_sched_barrier(0);                                       \
    if (STAGEA) gl_lds16(srcA + (size_t)((T) + 2) * 4096, DN);               \
    const u16* rb_ = ldsA + (RB) * 4096;                                     \
    bf16x8 av0 = *(const bf16x8*)(rb_);                                      \
    bf16x8 av1 = *(const bf16x8*)(rb_ + 512);                                \
    bf16x8 av2 = *(const bf16x8*)(rb_ + 1024);                               \
    bf16x8 av3 = *(const bf16x8*)(rb_ + 1536);                               \
    __builtin_amdgcn_s_setprio(1);                                           \
    acc[0][0]=mf(av0,U0,acc[0][0]); acc[0][1]=mf(av0,U1,acc[0][1]);          \
    acc[0][2]=mf(av0,U2,acc[0][2]); acc[0][3]=mf(av0,U3,acc[0][3]);          \
    acc[1][0]=mf(av1,U0,acc[1][0]); acc[1][1]=mf(av1,U1,acc[1][1]);          \
    acc[1][2]=mf(av1,U2,acc[1][2]); acc[1][3]=mf(av1,U3,acc[1][3]);          \
    acc[2][0]=mf(av2,U0,acc[2][0]); acc[2][1]=mf(av2,U1,acc[2][1]);          \
    acc[2][2]=mf(av2,U2,acc[2][2]); acc[2][3]=mf(av2,U3,acc[2][3]);          \
    acc[3][0]=mf(av3,U0,acc[3][0]); acc[3][1]=mf(av3,U1,acc[3][1]);          \
    acc[3][2]=mf(av3,U2,acc[3][2]); acc[3][3]=mf(av3,U3,acc[3][3]);          \
    __builtin_amdgcn_s_setprio(0);                                           \
    if ((WMODE) == 0)      asm volatile("s_waitcnt vmcnt(1)" ::: "memory");  \
    else if ((WMODE) == 1) asm volatile("s_waitcnt vmcnt(0)" ::: "memory");  \
    if ((WMODE) != 2)      asm volatile("s_barrier" ::: "memory");           \
  }

  for (int t6 = 0; t6 < 30; t6 += 6) {            // slot period 3 x parity 2 = 6
    GBODY(t6 + 0, 0, d2, A0,A1,A2,A3, B0,B1,B2,B3, 1, 1, 0)
    GBODY(t6 + 1, 1, d0, B0,B1,B2,B3, A0,A1,A2,A3, 1, 1, 0)
    GBODY(t6 + 2, 2, d1, A0,A1,A2,A3, B0,B1,B2,B3, 1, 1, 0)
    GBODY(t6 + 3, 0, d2, B0,B1,B2,B3, A0,A1,A2,A3, 1, 1, 0)
    GBODY(t6 + 4, 1, d0, A0,A1,A2,A3, B0,B1,B2,B3, 1, 1, 0)
    GBODY(t6 + 5, 2, d1, B0,B1,B2,B3, A0,A1,A2,A3, 1, 1, 0)
  }
  GBODY(30, 0, d2, A0,A1,A2,A3, B0,B1,B2,B3, 1, 0, 1)
  GBODY(31, 1, d0, B0,B1,B2,B3, A0,A1,A2,A3, 0, 0, 2)
#undef GBODY

  const bool act = (bx >= 4);                     // f/r panels -> sigmoid
#pragma unroll
  for (int m = 0; m < 4; ++m) {
    const int row0 = by * 128 + wm * 64 + m * 16 + lk * 4;
#pragma unroll
    for (int n = 0; n < 4; ++n) {
      const int col = bx * 256 + wn * 64 + n * 16 + lr;
#pragma unroll
      for (int j = 0; j < 4; ++j) {
        float v = acc[m][n][j];
        if (act) v = 1.f / (1.f + __expf(-v));
        C[(size_t)(row0 + j) * N3 + col] = f2b(v);
      }
    }
  }
}

// ---------------- K1 fallback: f32-input reg-staged GEMM (validated r1) --------
__global__ __launch_bounds__(256) void k_gemm_reg(const float* __restrict__ A,
                                                  const float* __restrict__ B,
                                                  u16* __restrict__ C) {
  __shared__ u16 lds[8192];
  const int tid  = threadIdx.x;
  const int lane = tid & 63;
  const int wid  = tid >> 6;
  const int wm = wid >> 1, wn = wid & 1;
  const int lr = lane & 15, lk = lane >> 4;
  const int mBase = blockIdx.y << 7;
  const int nBase = blockIdx.x << 7;

  f32x4 acc[4][4] = {};
  const int aoff = (wm * 64 + lr) * 32 + lk * 8;
  const int boff = 4096 + (wn * 64 + lr) * 32 + lk * 8;

  for (int k0 = 0; k0 < DIM; k0 += 32) {
#pragma unroll
    for (int q = 0; q < 4; ++q) {
      const int i  = q * 256 + tid;
      const int rr = i >> 3;
      const int cc = (i & 7) << 2;
      float4 va = *(const float4*)(A + (size_t)(mBase + rr) * DIM + k0 + cc);
      float4 vb = *(const float4*)(B + (size_t)(nBase + rr) * DIM + k0 + cc);
      uint2 pa; pa.x = pk2(va.x, va.y); pa.y = pk2(va.z, va.w);
      uint2 pb; pb.x = pk2(vb.x, vb.y); pb.y = pk2(vb.z, vb.w);
      *(uint2*)&lds[rr * 32 + cc] = pa;
      *(uint2*)&lds[4096 + rr * 32 + cc] = pb;
    }
    __syncthreads();
    bf16x8 av[4], bv[4];
#pragma unroll
    for (int m = 0; m < 4; ++m) av[m] = *(const bf16x8*)&lds[aoff + m * 512];
#pragma unroll
    for (int n = 0; n < 4; ++n) bv[n] = *(const bf16x8*)&lds[boff + n * 512];
#pragma unroll
    for (int m = 0; m < 4; ++m)
#pragma unroll
      for (int n = 0; n < 4; ++n)
        acc[m][n] = mf(av[m], bv[n], acc[m][n]);
    __syncthreads();
  }

  const bool act = (nBase >= DIM);
#pragma unroll
  for (int m = 0; m < 4; ++m) {
    const int row0 = mBase + wm * 64 + m * 16 + lk * 4;
#pragma unroll
    for (int n = 0; n < 4; ++n) {
      const int col = nBase + wn * 64 + n * 16 + lr;
#pragma unroll
      for (int j = 0; j < 4; ++j) {
        float v = acc[m][n][j];
        if (act) v = 1.f / (1.f + __expf(-v));
        C[(size_t)(row0 + j) * N3 + col] = f2b(v);
      }
    }
  }
}

// ---------------- K2: chunk-local affine coefficients --------------------------
__global__ void k_scanA(const u16* __restrict__ ufr, float* __restrict__ P,
                        float* __restrict__ V) {
  int g = blockIdx.x * 256 + threadIdx.x;
  int j = g >> 13;
  int chain = g & (NCHAIN - 1);
  int b = chain >> 10;
  int d = chain & (DIM - 1);
  const u16* p = ufr + (size_t)((j * LCHUNK) * BATCH + b) * N3 + d;
  float prod = 1.f, v = 0.f;
  for (int t = 0; t < LCHUNK; ++t) {
    float u = b2f(p[0]);
    float f = b2f(p[DIM]);
    v = f * v + (1.f - f) * u;
    prod *= f;
    p += BATCH * N3;
  }
  P[g] = prod; V[g] = v;
}

// ---------------- K3: sequential combine over chunks ---------------------------
__global__ void k_scanB(const float* __restrict__ c0, const float* __restrict__ P,
                        const float* __restrict__ V, float* __restrict__ S,
                        float* __restrict__ lastc) {
  int chain = blockIdx.x * 256 + threadIdx.x;
  float c = c0[chain];
  for (int j = 0; j < NCHUNK; ++j) {
    S[j * NCHAIN + chain] = c;
    c = P[j * NCHAIN + chain] * c + V[j * NCHAIN + chain];
  }
  lastc[chain] = c;
}

// ---------------- K4: fused replay + hs + gelu + LayerNorm (prefetched) --------
__global__ __launch_bounds__(1024) void k_scanln(const u16* __restrict__ ufr,
                                                 const float* __restrict__ S,
                                                 const float* __restrict__ x,
                                                 const float* __restrict__ lnw,
                                                 const float* __restrict__ lnb,
                                                 float* __restrict__ out) {
  const int j = blockIdx.x >> 3;                  // chunk 0..63
  const int b = blockIdx.x & 7;
  const int d = threadIdx.x;
  const int lane = d & 63, wid = d >> 6;

  float c = S[j * NCHAIN + b * DIM + d];
  const float wgt = lnw[d];
  const float bia = lnb[d];

  const u16*   pu = ufr + (size_t)((j * LCHUNK) * BATCH + b) * N3 + d;
  const float* px = x   + (size_t)((j * LCHUNK) * BATCH + b) * DIM + d;
  float*       po = out + (size_t)((j * LCHUNK) * BATCH + b) * DIM + d;

  __shared__ float red1[16], red2[16];

  u16 cu = pu[0], cf = pu[DIM], cr = pu[2 * DIM];
  float cx = *px;

  for (int t = 0; t < LCHUNK; ++t) {
    const int adv = (t < LCHUNK - 1) ? 1 : 0;
    u16 nu = pu[(size_t)adv * BATCH * N3];
    u16 nf = pu[(size_t)adv * BATCH * N3 + DIM];
    u16 nr = pu[(size_t)adv * BATCH * N3 + 2 * DIM];
    float nx = px[(size_t)adv * BATCH * DIM];

    float u = b2f(cu), f = b2f(cf), rr = b2f(cr), xx = cx;
    c = f * c + (1.f - f) * u;
    float hs = rr * tanhf(c) + (1.f - rr) * xx;
    float g  = 0.5f * hs * (1.f + erff(hs * 0.70710678118654752f));

    float s1 = g, s2 = g * g;
#pragma unroll
    for (int off = 32; off > 0; off >>= 1) {
      s1 += __shfl_down(s1, off, 64);
      s2 += __shfl_down(s2, off, 64);
    }
    if (lane == 0) { red1[wid] = s1; red2[wid] = s2; }
    __syncthreads();
    float S1 = 0.f, S2 = 0.f;
#pragma unroll
    for (int w = 0; w < 16; ++w) { S1 += red1[w]; S2 += red2[w]; }
    float mu  = S1 * (1.f / DIM);
    float var = S2 * (1.f / DIM) - mu * mu;
    float inv = rsqrtf(var + 1e-5f);
    *po = (g - mu) * inv * wgt + bia;
    __syncthreads();

    cu = nu; cf = nf; cr = nr; cx = nx;
    pu += BATCH * N3;
    px += BATCH * DIM;
    po += BATCH * DIM;
  }
}

extern "C" void kernel_launch(void* const* d_in, const int* in_sizes, int n_in,
                              void* d_out, int out_size, void* d_ws, size_t ws_size,
                              hipStream_t stream) {
  (void)in_sizes; (void)n_in; (void)out_size;
  const float* x   = (const float*)d_in[0];
  const float* c0  = (const float*)d_in[1];
  const float* W   = (const float*)d_in[2];
  const float* lnw = (const float*)d_in[3];
  const float* lnb = (const float*)d_in[4];
  float* out   = (float*)d_out;                   // (L,B,D) f32
  float* lastc = out + (size_t)ROWS * DIM;        // (B,D)   f32

  char* ws = (char*)d_ws;

  u16* ufr; float *P, *V, *S;
  const size_t FULL_NEED = 140509184;             // apk + wpk + ufr (P/V/S alias apk)
  if (ws_size >= FULL_NEED) {
    u16* apk = (u16*)ws;                          // 33,554,432 B (dead after GEMM)
    u16* wpk = (u16*)(ws + 33554432);             //  6,291,456 B
    ufr = (u16*)(ws + 39845888);                  // 100,663,296 B
    P   = (float*)ws;                             // alias apk region
    V   = (float*)(ws + 2097152);
    S   = (float*)(ws + 4194304);
    k_pack<<<2048, 256, 0, stream>>>(x, W, apk, wpk);
    k_gemm_v4<<<1536, 512, 0, stream>>>(apk, wpk, ufr);
  } else {
    ufr = (u16*)ws;
    P   = (float*)(ws + 100663296);
    V   = (float*)(ws + 102760448);
    S   = (float*)(ws + 104857600);
    dim3 g1(N3 / 128, ROWS / 128);
    k_gemm_reg<<<g1, 256, 0, stream>>>(x, W, ufr);
  }

  k_scanA<<<(NCHUNK * NCHAIN) / 256, 256, 0, stream>>>(ufr, P, V);
  k_scanB<<<NCHAIN / 256, 256, 0, stream>>>(c0, P, V, S, lastc);
  k_scanln<<<NCHUNK * BATCH, 1024, 0, stream>>>(ufr, S, x, lnw, lnb, out);
}